// Round 7
// baseline (71.937 us; speedup 1.0000x reference)
//
#include <hip/hip_runtime.h>
#include <hip/hip_bf16.h>

// out[m,u] = sum_t x[m,t] * W_eff[u,t] + b_eff[u]      (m = 32*512 rows)
//   W_eff = Ws + (Wt - Ws) @ A   (A = causal window-mean, window 25)
// Round-7: round-6 structure (x-tile in LDS, ONE barrier, W streamed
// global->reg, zero-barrier K-loop) resized BM 64->48 so LDS = 71.4 KB
// -> 2 blocks/CU resident (16 waves/CU): cross-block phase overlap.

#define Tdim  720
#define KP    736      // padded K (23*32); Wb zero-filled for k>=720
#define WROWS 768      // padded u-rows of Wb (zero rows >=720)
#define NK    23
#define BM    48       // m-rows per block (48*744*2B = 71424 B LDS)
#define APAD  744      // LDS row stride in elems (stride%32dw==20 -> benign 2-way)

using bf16x8 = __attribute__((ext_vector_type(8))) __bf16;
using f32x4  = __attribute__((ext_vector_type(4))) float;

__global__ void fold_w_kernel(const float* __restrict__ tw,
                              const float* __restrict__ tb,
                              const float* __restrict__ sw,
                              const float* __restrict__ sb,
                              __bf16* __restrict__ Wb,
                              float* __restrict__ beff) {
  int idx = blockIdx.x * 256 + threadIdx.x;
  if (idx >= WROWS * KP) return;
  int u = idx / KP;
  int i = idx - u * KP;
  float w = 0.0f;
  if (u < Tdim && i < Tdim) {
    const float* twr = tw + (size_t)u * Tdim;
    const float* swr = sw + (size_t)u * Tdim;
    int tend = (i + 25 < Tdim) ? (i + 25) : Tdim;
    float acc = 0.0f;
    if (i >= 24) {
      #pragma unroll 5
      for (int t = i; t < tend; ++t) acc += twr[t] - swr[t];
      acc *= 0.04f;
    } else {
      for (int t = i; t < tend; ++t) {
        float c = (t >= 24) ? 0.04f : 1.0f / (float)(t + 1);
        acc += (twr[t] - swr[t]) * c;
      }
    }
    w = swr[i] + acc;
  }
  Wb[idx] = (__bf16)w;
  if (i == 0 && u < Tdim) beff[u] = tb[u] + sb[u];
}

__global__ __launch_bounds__(512, 4)
void dlinear_gemm(const float* __restrict__ x,
                  const __bf16* __restrict__ Wb,
                  const float* __restrict__ beff,
                  float* __restrict__ out, int Mtotal) {
  __shared__ __bf16 As[BM * APAD];   // 71424 B -> 2 blocks/CU

  const int tid  = threadIdx.x;
  const int lane = tid & 63;
  const int wid  = tid >> 6;          // 0..7
  const int lg = lane >> 4, lr = lane & 15;

  int m0 = blockIdx.x * BM;
  if (m0 > Mtotal - BM) m0 = Mtotal - BM;   // last block overlaps; identical writes
  const int u0 = wid * 96;            // wave owns 96 u-cols (768 = 8*96 padded)

  // ---- prologue: x[m0..m0+48) x [0..720) -> LDS bf16 (coalesced 32B/lane)
  #pragma unroll
  for (int c = 0; c < 9; ++c) {
    int idx = tid + 512 * c;          // 8-f32 chunk id; 90 chunks per row
    if (idx < BM * 90) {
      int row  = idx / 90;
      int col8 = idx - row * 90;
      const float* p = x + (size_t)(m0 + row) * Tdim + col8 * 8;
      f32x4 a0 = ((const f32x4*)p)[0];
      f32x4 a1 = ((const f32x4*)p)[1];
      bf16x8 v;
      #pragma unroll
      for (int j = 0; j < 4; ++j) { v[j] = (__bf16)a0[j]; v[j + 4] = (__bf16)a1[j]; }
      *(bf16x8*)(&As[row * APAD + col8 * 8]) = v;
    }
  }
  {  // zero the K-pad [720,736): garbage here could be NaN; W pad is exact 0
    int r = tid >> 3;
    if (r < BM) {
      int c = 720 + (tid & 7) * 2;
      As[r * APAD + c]     = (__bf16)0.0f;
      As[r * APAD + c + 1] = (__bf16)0.0f;
    }
  }
  __syncthreads();                    // the ONLY barrier

  // ---- W stream pointers: frag ni -> row u0+ni*16+lr, 16B chunk lg within K-step
  const __bf16* wp[6];
  #pragma unroll
  for (int ni = 0; ni < 6; ++ni)
    wp[ni] = Wb + (size_t)(u0 + ni * 16 + lr) * KP + lg * 8;

  int arofs[3];
  #pragma unroll
  for (int mi = 0; mi < 3; ++mi) arofs[mi] = (mi * 16 + lr) * APAD + lg * 8;

  f32x4 acc[3][6];
  #pragma unroll
  for (int mi = 0; mi < 3; ++mi)
    #pragma unroll
    for (int ni = 0; ni < 6; ++ni) {
      f32x4 z; z[0] = 0.f; z[1] = 0.f; z[2] = 0.f; z[3] = 0.f;
      acc[mi][ni] = z;
    }

  // ---- K-loop: named 2-stage pipeline, zero barriers
  bf16x8 b0[6], b1[6];
  #pragma unroll
  for (int ni = 0; ni < 6; ++ni) b0[ni] = *(const bf16x8*)wp[ni];   // t=0

  for (int t = 0; t < NK - 1; t += 2) {   // t = 0,2,...,20
    // even step t: consume b0, prefetch t+1 into b1
    #pragma unroll
    for (int ni = 0; ni < 6; ++ni) b1[ni] = *(const bf16x8*)(wp[ni] + (t + 1) * 32);
    {
      bf16x8 av[3];
      #pragma unroll
      for (int mi = 0; mi < 3; ++mi) av[mi] = *(const bf16x8*)(&As[arofs[mi] + t * 32]);
      #pragma unroll
      for (int mi = 0; mi < 3; ++mi)
        #pragma unroll
        for (int ni = 0; ni < 6; ++ni)
          acc[mi][ni] = __builtin_amdgcn_mfma_f32_16x16x32_bf16(av[mi], b0[ni],
                                                                acc[mi][ni], 0, 0, 0);
    }
    // odd step t+1: consume b1, prefetch t+2 into b0 (t+2 <= 22 always valid)
    #pragma unroll
    for (int ni = 0; ni < 6; ++ni) b0[ni] = *(const bf16x8*)(wp[ni] + (t + 2) * 32);
    {
      bf16x8 av[3];
      #pragma unroll
      for (int mi = 0; mi < 3; ++mi) av[mi] = *(const bf16x8*)(&As[arofs[mi] + (t + 1) * 32]);
      #pragma unroll
      for (int mi = 0; mi < 3; ++mi)
        #pragma unroll
        for (int ni = 0; ni < 6; ++ni)
          acc[mi][ni] = __builtin_amdgcn_mfma_f32_16x16x32_bf16(av[mi], b1[ni],
                                                                acc[mi][ni], 0, 0, 0);
    }
  }
  {  // tail t = 22 consumes b0
    bf16x8 av[3];
    #pragma unroll
    for (int mi = 0; mi < 3; ++mi) av[mi] = *(const bf16x8*)(&As[arofs[mi] + 22 * 32]);
    #pragma unroll
    for (int mi = 0; mi < 3; ++mi)
      #pragma unroll
      for (int ni = 0; ni < 6; ++ni)
        acc[mi][ni] = __builtin_amdgcn_mfma_f32_16x16x32_bf16(av[mi], b0[ni],
                                                              acc[mi][ni], 0, 0, 0);
  }

  // ---- epilogue: C/D layout col = lr -> u, row = lg*4 + j -> m
  #pragma unroll
  for (int ni = 0; ni < 6; ++ni) {
    const int u = u0 + ni * 16 + lr;
    if (u >= Tdim) continue;
    const float bias = beff[u];
    #pragma unroll
    for (int mi = 0; mi < 3; ++mi) {
      const int mb = m0 + mi * 16 + lg * 4;
      #pragma unroll
      for (int j = 0; j < 4; ++j)
        out[(size_t)(mb + j) * Tdim + u] = acc[mi][ni][j] + bias;
    }
  }
}

extern "C" void kernel_launch(void* const* d_in, const int* in_sizes, int n_in,
                              void* d_out, int out_size, void* d_ws, size_t ws_size,
                              hipStream_t stream) {
  const float* x  = (const float*)d_in[0];
  const float* tw = (const float*)d_in[1];
  const float* tb = (const float*)d_in[2];
  const float* sw = (const float*)d_in[3];
  const float* sb = (const float*)d_in[4];
  float* out = (float*)d_out;

  __bf16* Wb  = (__bf16*)d_ws;
  float* beff = (float*)((char*)d_ws + (size_t)WROWS * KP * sizeof(__bf16));

  const int fold_total = WROWS * KP;
  fold_w_kernel<<<dim3((fold_total + 255) / 256), dim3(256), 0, stream>>>(
      tw, tb, sw, sb, Wb, beff);

  const int M = in_sizes[0] / Tdim;            // 16384
  dim3 grid((M + BM - 1) / BM);                // 342 blocks
  dlinear_gemm<<<grid, dim3(512), 0, stream>>>(x, Wb, beff, out, M);
}

// Round 8
// 49.085 us; speedup vs baseline: 1.4656x; 1.4656x over previous
//
#include <hip/hip_runtime.h>
#include <hip/hip_bf16.h>

// out[m,u] = sum_t x[m,t] * W_eff[u,t] + b_eff[u]      (m = 32*512 rows)
//   W_eff = Ws + (Wt - Ws) @ A   (A = causal window-mean, window 25)
// Round-8: round-6 structure (x-tile in LDS, ONE barrier, W streamed
// global->reg, zero-barrier K-loop) with 1024 threads / 16 waves per block
// (4 waves/SIMD) — TLP inside the block instead of a second resident block.
// Wave owns 48 u-cols (3 N-frags); acc 4x3; VGPR ~110 < 128 cap (no spill).

#define Tdim  720
#define KP    736      // padded K (23*32); Wb zero-filled for k>=720
#define WROWS 768      // padded u-rows of Wb (zero rows >=720)
#define NK    23
#define BM    64       // m-rows per block
#define APAD  744      // LDS row stride in elems (2-way bank alias, free per m136)

using bf16x8 = __attribute__((ext_vector_type(8))) __bf16;
using f32x4  = __attribute__((ext_vector_type(4))) float;

__global__ void fold_w_kernel(const float* __restrict__ tw,
                              const float* __restrict__ tb,
                              const float* __restrict__ sw,
                              const float* __restrict__ sb,
                              __bf16* __restrict__ Wb,
                              float* __restrict__ beff) {
  int idx = blockIdx.x * 256 + threadIdx.x;
  if (idx >= WROWS * KP) return;
  int u = idx / KP;
  int i = idx - u * KP;
  float w = 0.0f;
  if (u < Tdim && i < Tdim) {
    const float* twr = tw + (size_t)u * Tdim;
    const float* swr = sw + (size_t)u * Tdim;
    int tend = (i + 25 < Tdim) ? (i + 25) : Tdim;
    float acc = 0.0f;
    if (i >= 24) {
      #pragma unroll 5
      for (int t = i; t < tend; ++t) acc += twr[t] - swr[t];
      acc *= 0.04f;
    } else {
      for (int t = i; t < tend; ++t) {
        float c = (t >= 24) ? 0.04f : 1.0f / (float)(t + 1);
        acc += (twr[t] - swr[t]) * c;
      }
    }
    w = swr[i] + acc;
  }
  Wb[idx] = (__bf16)w;
  if (i == 0 && u < Tdim) beff[u] = tb[u] + sb[u];
}

__global__ __launch_bounds__(1024, 1)
void dlinear_gemm(const float* __restrict__ x,
                  const __bf16* __restrict__ Wb,
                  const float* __restrict__ beff,
                  float* __restrict__ out) {
  __shared__ __bf16 As[BM * APAD];   // 95232 B -> 1 block/CU

  const int tid  = threadIdx.x;
  const int lane = tid & 63;
  const int wid  = tid >> 6;          // 0..15
  const int lg = lane >> 4, lr = lane & 15;

  const int m0 = blockIdx.x * BM;
  const int u0 = wid * 48;            // wave owns 48 u-cols (768 = 16*48 padded)

  // ---- prologue: x[m0..m0+64) x [0..720) -> LDS bf16 (coalesced 32B/lane)
  #pragma unroll
  for (int c = 0; c < 6; ++c) {
    int idx = tid + 1024 * c;         // 8-f32 chunk id; 90 chunks per row
    if (idx < BM * 90) {
      int row  = idx / 90;
      int col8 = idx - row * 90;
      const float* p = x + (size_t)(m0 + row) * Tdim + col8 * 8;
      f32x4 a0 = ((const f32x4*)p)[0];
      f32x4 a1 = ((const f32x4*)p)[1];
      bf16x8 v;
      #pragma unroll
      for (int j = 0; j < 4; ++j) { v[j] = (__bf16)a0[j]; v[j + 4] = (__bf16)a1[j]; }
      *(bf16x8*)(&As[row * APAD + col8 * 8]) = v;
    }
  }
  {  // zero the K-pad [720,736): 64 rows x 16 elems = 1024 threads exactly
    int r = tid >> 4;
    int c = 720 + (tid & 15);
    As[r * APAD + c] = (__bf16)0.0f;
  }
  __syncthreads();                    // the ONLY barrier

  // ---- W stream pointers: frag ni -> row u0+ni*16+lr, 16B chunk lg within K-step
  const __bf16* wp[3];
  #pragma unroll
  for (int ni = 0; ni < 3; ++ni)
    wp[ni] = Wb + (size_t)(u0 + ni * 16 + lr) * KP + lg * 8;

  int arofs[4];
  #pragma unroll
  for (int mi = 0; mi < 4; ++mi) arofs[mi] = (mi * 16 + lr) * APAD + lg * 8;

  f32x4 acc[4][3];
  #pragma unroll
  for (int mi = 0; mi < 4; ++mi)
    #pragma unroll
    for (int ni = 0; ni < 3; ++ni) {
      f32x4 z; z[0] = 0.f; z[1] = 0.f; z[2] = 0.f; z[3] = 0.f;
      acc[mi][ni] = z;
    }

  // ---- K-loop: named 2-stage pipeline, zero barriers
  bf16x8 b0[3], b1[3];
  #pragma unroll
  for (int ni = 0; ni < 3; ++ni) b0[ni] = *(const bf16x8*)wp[ni];   // t=0

  for (int t = 0; t < NK - 1; t += 2) {   // t = 0,2,...,20
    // even step t: consume b0, prefetch t+1 into b1
    #pragma unroll
    for (int ni = 0; ni < 3; ++ni) b1[ni] = *(const bf16x8*)(wp[ni] + (t + 1) * 32);
    {
      bf16x8 av[4];
      #pragma unroll
      for (int mi = 0; mi < 4; ++mi) av[mi] = *(const bf16x8*)(&As[arofs[mi] + t * 32]);
      #pragma unroll
      for (int mi = 0; mi < 4; ++mi)
        #pragma unroll
        for (int ni = 0; ni < 3; ++ni)
          acc[mi][ni] = __builtin_amdgcn_mfma_f32_16x16x32_bf16(av[mi], b0[ni],
                                                                acc[mi][ni], 0, 0, 0);
    }
    // odd step t+1: consume b1, prefetch t+2 into b0 (t+2 <= 22 always valid)
    #pragma unroll
    for (int ni = 0; ni < 3; ++ni) b0[ni] = *(const bf16x8*)(wp[ni] + (t + 2) * 32);
    {
      bf16x8 av[4];
      #pragma unroll
      for (int mi = 0; mi < 4; ++mi) av[mi] = *(const bf16x8*)(&As[arofs[mi] + (t + 1) * 32]);
      #pragma unroll
      for (int mi = 0; mi < 4; ++mi)
        #pragma unroll
        for (int ni = 0; ni < 3; ++ni)
          acc[mi][ni] = __builtin_amdgcn_mfma_f32_16x16x32_bf16(av[mi], b1[ni],
                                                                acc[mi][ni], 0, 0, 0);
    }
  }
  {  // tail t = 22 consumes b0
    bf16x8 av[4];
    #pragma unroll
    for (int mi = 0; mi < 4; ++mi) av[mi] = *(const bf16x8*)(&As[arofs[mi] + 22 * 32]);
    #pragma unroll
    for (int mi = 0; mi < 4; ++mi)
      #pragma unroll
      for (int ni = 0; ni < 3; ++ni)
        acc[mi][ni] = __builtin_amdgcn_mfma_f32_16x16x32_bf16(av[mi], b0[ni],
                                                              acc[mi][ni], 0, 0, 0);
  }

  // ---- epilogue: C/D layout col = lr -> u, row = lg*4 + j -> m
  #pragma unroll
  for (int ni = 0; ni < 3; ++ni) {
    const int u = u0 + ni * 16 + lr;
    if (u >= Tdim) continue;
    const float bias = beff[u];
    #pragma unroll
    for (int mi = 0; mi < 4; ++mi) {
      const int mb = m0 + mi * 16 + lg * 4;
      #pragma unroll
      for (int j = 0; j < 4; ++j)
        out[(size_t)(mb + j) * Tdim + u] = acc[mi][ni][j] + bias;
    }
  }
}

extern "C" void kernel_launch(void* const* d_in, const int* in_sizes, int n_in,
                              void* d_out, int out_size, void* d_ws, size_t ws_size,
                              hipStream_t stream) {
  const float* x  = (const float*)d_in[0];
  const float* tw = (const float*)d_in[1];
  const float* tb = (const float*)d_in[2];
  const float* sw = (const float*)d_in[3];
  const float* sb = (const float*)d_in[4];
  float* out = (float*)d_out;

  __bf16* Wb  = (__bf16*)d_ws;
  float* beff = (float*)((char*)d_ws + (size_t)WROWS * KP * sizeof(__bf16));

  const int fold_total = WROWS * KP;
  fold_w_kernel<<<dim3((fold_total + 255) / 256), dim3(256), 0, stream>>>(
      tw, tb, sw, sb, Wb, beff);

  const int M = in_sizes[0] / Tdim;            // 16384
  dim3 grid(M / BM);                           // 256 blocks, 1 per CU
  dlinear_gemm<<<grid, dim3(1024), 0, stream>>>(x, Wb, beff, out);
}